// Round 11
// baseline (268.316 us; speedup 1.0000x reference)
//
#include <hip/hip_runtime.h>
#include <hip/hip_bf16.h>
#include <hip/hip_fp16.h>

#define N_NODES  100000
#define N_GRAPHS 512
#define IN_CH    128
#define HID      32
#define OUT_CH   10
#define N_EDGES  3200000

#define SZC   256                            // nodes per bucket
#define NBC   ((N_NODES + SZC - 1) / SZC)    // 391
#define CAPC  9216                           // mean 8192, +11 sigma
#define RND   2048                           // edges per binning round (small => many blocks)
#define EPT   8                              // edges per thread per round
#define NRND  ((N_EDGES + RND - 1) / RND)    // 1563

typedef _Float16 half8 __attribute__((ext_vector_type(8)));
typedef float    f32x4 __attribute__((ext_vector_type(4)));

// ---- int32/int64 index loader (low word of little-endian int64) ----
__device__ __forceinline__ int load_idx(const int* __restrict__ p, long long pos, int is64) {
  return is64 ? p[2 * pos] : p[(int)pos];
}

// unpack 8 consecutive halfs (loaded as float4) and accumulate into a[8]
__device__ __forceinline__ void h8_acc(float4 raw, float* a) {
  const __half2* ph = (const __half2*)&raw;
#pragma unroll
  for (int q = 0; q < 4; q++) {
    float2 f = __half22float2(ph[q]);
    a[2 * q]     += f.x;
    a[2 * q + 1] += f.y;
  }
}

// Detect whether index buffers are int64. block 0 -> ei flag, block 1 -> batch.
__global__ void detect_i64(const int* __restrict__ ei, const int* __restrict__ batch,
                           int* __restrict__ flag) {
  __shared__ int any_nz;
  const int* buf = (blockIdx.x == 0) ? ei : batch;
  if (threadIdx.x == 0) any_nz = 0;
  __syncthreads();
  for (int i = threadIdx.x; i < 4096; i += 256) {
    if (buf[2 * i + 1] != 0) any_nz = 1;
  }
  __syncthreads();
  if (threadIdx.x == 0) flag[blockIdx.x] = any_nz ? 0 : 1;
}

// ---- pack W[K][32] f32 into MFMA B-fragment order, fp16 ----
__global__ void pack_w(const float* __restrict__ W1, const float* __restrict__ W2,
                       const float* __restrict__ W3, __half* __restrict__ P1,
                       __half* __restrict__ P2, __half* __restrict__ P3) {
  int t = threadIdx.x;
  for (int idx = t; idx < 4 * 2 * 64 * 8; idx += 256) {   // W1: K=128 -> 4 k-steps
    int j = idx & 7, l = (idx >> 3) & 63, ct = (idx >> 9) & 1, s = idx >> 10;
    int k = s * 32 + (l >> 4) * 8 + j, c = ct * 16 + (l & 15);
    P1[idx] = __float2half(W1[k * 32 + c]);
  }
  for (int idx = t; idx < 2 * 64 * 8; idx += 256) {       // W2,W3: K=32 -> 1 k-step
    int j = idx & 7, l = (idx >> 3) & 63, ct = (idx >> 9) & 1;
    int k = (l >> 4) * 8 + j, c = ct * 16 + (l & 15);
    P2[idx] = __float2half(W2[k * 32 + c]);
    P3[idx] = __float2half(W3[k * 32 + c]);
  }
}

// ---- pass 1: round-based binning; 1563 blocks of 2048 edges for occupancy.
//      LDS hist over 391 buckets -> 1 global atomicAdd per (round,bucket)
//      reserves a contiguous run -> LDS-cursor scatter (dense run writes). ----
__global__ void bucket_k(const int* __restrict__ ei, const int* __restrict__ flag,
                         int* __restrict__ gcur, int* __restrict__ bstore) {
  __shared__ int hist[NBC];
  __shared__ int base[NBC];
  int is64 = flag[0];
  int t = threadIdx.x;
  int rd = blockIdx.x;
  for (int i = t; i < NBC; i += 256) hist[i] = 0;
  __syncthreads();
  long long e0 = (long long)rd * RND;
  int   pk[EPT];
  short cb[EPT];
#pragma unroll
  for (int k = 0; k < EPT; k++) {
    long long e = e0 + k * 256 + t;
    if (e < N_EDGES) {
      int s = load_idx(ei, e, is64);
      int d = load_idx(ei, N_EDGES + e, is64);
      pk[k] = (s << 8) | (d & 255);
      cb[k] = (short)(d >> 8);
      atomicAdd(&hist[d >> 8], 1);
    } else {
      cb[k] = -1;
    }
  }
  __syncthreads();
  for (int c = t; c < NBC; c += 256) {
    int h = hist[c];
    if (h > 0) base[c] = atomicAdd(&gcur[c], h);
  }
  __syncthreads();
#pragma unroll
  for (int k = 0; k < EPT; k++) {
    if (cb[k] >= 0) {
      int c = cb[k];
      int pos = atomicAdd(&base[c], 1);          // LDS cursor from global base
      if (pos < CAPC) bstore[(size_t)c * CAPC + pos] = pk[k];
    }
  }
}

// ---- exclusive scan of clamped coarse-bucket counts -> global bases ----
__global__ void bscan_k(const int* __restrict__ gcur, int* __restrict__ bbase) {
  __shared__ int part[256];
  int t = threadIdx.x;
  const int CHUNK = (NBC + 255) / 256;  // 2
  int v[CHUNK];
  int s = 0;
  int base = t * CHUNK;
  for (int k = 0; k < CHUNK; k++) {
    int i = base + k;
    v[k] = (i < NBC) ? min(gcur[i], CAPC) : 0;
    s += v[k];
  }
  part[t] = s;
  __syncthreads();
  if (t == 0) {
    int run = 0;
    for (int i = 0; i < 256; i++) { int x = part[i]; part[i] = run; run += x; }
  }
  __syncthreads();
  int run = part[t];
  for (int k = 0; k < CHUNK; k++) {
    int i = base + k;
    if (i < NBC) bbase[i] = run;
    run += v[k];
  }
}

// ---- per-bucket LDS counting sort -> per-node CSR + deg + dinv ----
__global__ void build_csr(const int* __restrict__ bstore, const int* __restrict__ gcur,
                          const int* __restrict__ bbase, int* __restrict__ csr,
                          int* __restrict__ row_ptr, int* __restrict__ deg,
                          float* __restrict__ dinv) {
  __shared__ int hist[SZC];
  __shared__ int sc[SZC];
  __shared__ int cur[SZC];
  int b = blockIdx.x, t = threadIdx.x;
  hist[t] = 0;
  __syncthreads();
  int cnt = min(gcur[b], CAPC);
  const int* eb = bstore + (size_t)b * CAPC;
  for (int i = t; i < cnt; i += 256) atomicAdd(&hist[eb[i] & 255], 1);
  __syncthreads();
  int own = hist[t];
  sc[t] = own;
  __syncthreads();
  for (int off = 1; off < SZC; off <<= 1) {
    int u = (t >= off) ? sc[t - off] : 0;
    __syncthreads();
    sc[t] += u;
    __syncthreads();
  }
  int excl = sc[t] - own;
  int gbase = bbase[b];
  int node = b * SZC + t;
  if (node < N_NODES) {
    row_ptr[node] = gbase + excl;
    deg[node]     = own;
    dinv[node]    = rsqrtf((float)(own + 1));  // +1 self-loop
  }
  cur[t] = excl;
  __syncthreads();
  for (int i = t; i < cnt; i += 256) {
    int pk = eb[i];                              // L2-hot (same block re-read)
    int pos = atomicAdd(&cur[pk & 255], 1);
    csr[gbase + pos] = pk >> 8;                  // dense ~33KB region, L2-resident
  }
}

// ---- MFMA GEMM: G = fp16( (X @ W) * dinv[row] ), no LDS, no barriers ----
template <int K>
__global__ void gemm_mfma(const float* __restrict__ X, const __half* __restrict__ P,
                          const float* __restrict__ dinv, __half* __restrict__ G) {
  int wid  = threadIdx.x >> 6;
  int lane = threadIdx.x & 63;
  int row0 = (blockIdx.x * 4 + wid) * 16;
  if (row0 >= N_NODES) return;
  int r  = lane & 15;    // A row within tile
  int ko = lane >> 4;    // k-octet selector
  f32x4 acc0 = {0.f, 0.f, 0.f, 0.f};
  f32x4 acc1 = {0.f, 0.f, 0.f, 0.f};
  const float* xrow = X + (size_t)(row0 + r) * K + ko * 8;
#pragma unroll
  for (int s = 0; s < K / 32; s++) {
    float4 xa = *(const float4*)(xrow + s * 32);
    float4 xb = *(const float4*)(xrow + s * 32 + 4);
    half8 a;
    a[0] = (_Float16)xa.x; a[1] = (_Float16)xa.y;
    a[2] = (_Float16)xa.z; a[3] = (_Float16)xa.w;
    a[4] = (_Float16)xb.x; a[5] = (_Float16)xb.y;
    a[6] = (_Float16)xb.z; a[7] = (_Float16)xb.w;
    half8 b0 = *(const half8*)(P + ((size_t)(s * 2 + 0) * 64 + lane) * 8);
    half8 b1 = *(const half8*)(P + ((size_t)(s * 2 + 1) * 64 + lane) * 8);
    acc0 = __builtin_amdgcn_mfma_f32_16x16x32_f16(a, b0, acc0, 0, 0, 0);
    acc1 = __builtin_amdgcn_mfma_f32_16x16x32_f16(a, b1, acc1, 0, 0, 0);
  }
  int col   = lane & 15;
  int rbase = row0 + (lane >> 4) * 4;
#pragma unroll
  for (int i = 0; i < 4; i++) {
    float dn = dinv[rbase + i];
    G[(size_t)(rbase + i) * 32 + col]      = __float2half(acc0[i] * dn);
    G[(size_t)(rbase + i) * 32 + 16 + col] = __float2half(acc1[i] * dn);
  }
}

// ---- pull aggregation: TWO 4-lane groups per node (even/odd edge halves),
//      8 nodes/wave, 12500 waves, 8 outstanding gathers per node ----
__global__ void agg_pull(const __half* __restrict__ g, const int* __restrict__ csr,
                         const int* __restrict__ row_ptr, const int* __restrict__ deg,
                         const float* __restrict__ dinv, const float* __restrict__ bias,
                         float* __restrict__ out, int do_relu) {
  int node = blockIdx.x * 32 + (threadIdx.x >> 3);
  if (node >= N_NODES) return;
  int half = (threadIdx.x >> 2) & 1;   // which half of the edge list
  int j    = threadIdx.x & 3;          // feature octet: halfs [j*8, j*8+8)
  const __half* gj = g + j * 8;
  int start = row_ptr[node];
  int dn = deg[node];
  float a0[8] = {0.f, 0.f, 0.f, 0.f, 0.f, 0.f, 0.f, 0.f};
  float a1[8] = {0.f, 0.f, 0.f, 0.f, 0.f, 0.f, 0.f, 0.f};
  float a2[8] = {0.f, 0.f, 0.f, 0.f, 0.f, 0.f, 0.f, 0.f};
  float a3[8] = {0.f, 0.f, 0.f, 0.f, 0.f, 0.f, 0.f, 0.f};
  int i = half;
  for (; i + 6 < dn; i += 8) {        // stride-2 within half, unroll 4
    int s0 = csr[start + i];
    int s1 = csr[start + i + 2];
    int s2 = csr[start + i + 4];
    int s3 = csr[start + i + 6];
    float4 r0 = *(const float4*)(gj + (size_t)s0 * HID);
    float4 r1 = *(const float4*)(gj + (size_t)s1 * HID);
    float4 r2 = *(const float4*)(gj + (size_t)s2 * HID);
    float4 r3 = *(const float4*)(gj + (size_t)s3 * HID);
    h8_acc(r0, a0);
    h8_acc(r1, a1);
    h8_acc(r2, a2);
    h8_acc(r3, a3);
  }
  for (; i < dn; i += 2) {
    int s0 = csr[start + i];
    h8_acc(*(const float4*)(gj + (size_t)s0 * HID), a0);
  }
#pragma unroll
  for (int k = 0; k < 8; k++) a0[k] += a1[k] + a2[k] + a3[k];
  // combine the two half-streams (lanes differ in bit 2)
#pragma unroll
  for (int k = 0; k < 8; k++) a0[k] += __shfl_xor(a0[k], 4, 64);
  if (half == 0) {
    float self[8] = {0.f, 0.f, 0.f, 0.f, 0.f, 0.f, 0.f, 0.f};
    h8_acc(*(const float4*)(gj + (size_t)node * HID), self);
    float dnv = dinv[node];
    float4 bb0 = *(const float4*)(bias + j * 8);
    float4 bb1 = *(const float4*)(bias + j * 8 + 4);
    float bbv[8] = {bb0.x, bb0.y, bb0.z, bb0.w, bb1.x, bb1.y, bb1.z, bb1.w};
    float r[8];
#pragma unroll
    for (int k = 0; k < 8; k++) {
      r[k] = dnv * (a0[k] + self[k]) + bbv[k];
      if (do_relu) r[k] = fmaxf(r[k], 0.f);
    }
    *(float4*)(out + (size_t)node * HID + j * 8)     = make_float4(r[0], r[1], r[2], r[3]);
    *(float4*)(out + (size_t)node * HID + j * 8 + 4) = make_float4(r[4], r[5], r[6], r[7]);
  }
}

// ---- fused mean-pool + linear head; batch is SORTED -> contiguous ranges ----
__global__ void pool_head(const float* __restrict__ h, const int* __restrict__ batch,
                          const int* __restrict__ flag, const float* __restrict__ Wl,
                          const float* __restrict__ bl, float* __restrict__ out) {
  __shared__ float acc[8][HID];
  int g = blockIdx.x, t = threadIdx.x;
  int is64 = flag[1];
  int start, end;
  {
    int lo = 0, hi = N_NODES;
    while (lo < hi) { int m = (lo + hi) >> 1; if (load_idx(batch, m, is64) < g) lo = m + 1; else hi = m; }
    start = lo;
    lo = start; hi = N_NODES;
    while (lo < hi) { int m = (lo + hi) >> 1; if (load_idx(batch, m, is64) < g + 1) lo = m + 1; else hi = m; }
    end = lo;
  }
  int c = t & 31, r = t >> 5;
  float s = 0.f;
  for (int i = start + r; i < end; i += 8) s += h[(size_t)i * HID + c];
  acc[r][c] = s;
  __syncthreads();
  if (t < HID) {
    float v = 0.f;
#pragma unroll
    for (int q = 0; q < 8; q++) v += acc[q][t];
    acc[0][t] = v / fmaxf((float)(end - start), 1.0f);
  }
  __syncthreads();
  if (t < OUT_CH) {
    float o = bl[t];
#pragma unroll
    for (int k = 0; k < HID; k++) o += acc[0][k] * Wl[k * OUT_CH + t];
    out[g * OUT_CH + t] = o;
  }
}

extern "C" void kernel_launch(void* const* d_in, const int* in_sizes, int n_in,
                              void* d_out, int out_size, void* d_ws, size_t ws_size,
                              hipStream_t stream) {
  const float* x   = (const float*)d_in[0];
  const int* ei    = (const int*)d_in[1];
  const int* batch = (const int*)d_in[2];
  const float* W1  = (const float*)d_in[3];
  const float* b1  = (const float*)d_in[4];
  const float* W2  = (const float*)d_in[5];
  const float* b2  = (const float*)d_in[6];
  const float* W3  = (const float*)d_in[7];
  const float* b3  = (const float*)d_in[8];
  const float* Wl  = (const float*)d_in[9];
  const float* bl  = (const float*)d_in[10];
  float* out = (float*)d_out;

  char* p = (char*)d_ws;
  auto alloc = [&](size_t bytes) {
    void* r = (void*)p;
    p += (bytes + 255) & ~(size_t)255;
    return r;
  };
  int*    gcur    = (int*)alloc((size_t)NBC * 4);
  int*    bbase   = (int*)alloc((size_t)NBC * 4);
  int*    bstore  = (int*)alloc((size_t)NBC * CAPC * 4);  // 14.4 MB
  int*    csr     = (int*)alloc((size_t)N_EDGES * 4);     // 12.8 MB
  int*    row_ptr = (int*)alloc((size_t)N_NODES * 4);
  int*    deg     = (int*)alloc((size_t)N_NODES * 4);
  float*  dinv    = (float*)alloc((size_t)N_NODES * 4);
  int*    flag    = (int*)alloc(8);
  __half* g       = (__half*)alloc((size_t)N_NODES * HID * 2);  // 6.4 MB fp16
  float*  h       = (float*)alloc((size_t)N_NODES * HID * 4);
  __half* P1      = (__half*)alloc((size_t)4 * 2 * 64 * 8 * 2); // 8 KB
  __half* P2      = (__half*)alloc((size_t)2 * 64 * 8 * 2);     // 2 KB
  __half* P3      = (__half*)alloc((size_t)2 * 64 * 8 * 2);     // 2 KB

  hipMemsetAsync(gcur, 0, (size_t)NBC * 4, stream);

  detect_i64<<<2, 256, 0, stream>>>(ei, batch, flag);
  pack_w<<<1, 256, 0, stream>>>(W1, W2, W3, P1, P2, P3);
  bucket_k<<<NRND, 256, 0, stream>>>(ei, flag, gcur, bstore);
  bscan_k<<<1, 256, 0, stream>>>(gcur, bbase);
  build_csr<<<NBC, 256, 0, stream>>>(bstore, gcur, bbase, csr, row_ptr, deg, dinv);

  const int GB = (N_NODES / 16 + 3) / 4;   // 1563 blocks for gemm
  const int AB = (N_NODES + 31) / 32;      // 3125 blocks for agg (8 nodes/wave)
  gemm_mfma<IN_CH><<<GB, 256, 0, stream>>>(x, P1, dinv, g);
  agg_pull<<<AB, 256, 0, stream>>>(g, csr, row_ptr, deg, dinv, b1, h, 1);
  gemm_mfma<HID><<<GB, 256, 0, stream>>>(h, P2, dinv, g);
  agg_pull<<<AB, 256, 0, stream>>>(g, csr, row_ptr, deg, dinv, b2, h, 1);
  gemm_mfma<HID><<<GB, 256, 0, stream>>>(h, P3, dinv, g);
  agg_pull<<<AB, 256, 0, stream>>>(g, csr, row_ptr, deg, dinv, b3, h, 0);

  pool_head<<<N_GRAPHS, 256, 0, stream>>>(h, batch, flag, Wl, bl, out);
}

// Round 12
// 237.472 us; speedup vs baseline: 1.1299x; 1.1299x over previous
//
#include <hip/hip_runtime.h>
#include <hip/hip_bf16.h>
#include <hip/hip_fp16.h>

#define N_NODES  100000
#define N_GRAPHS 512
#define IN_CH    128
#define HID      32
#define OUT_CH   10
#define N_EDGES  3200000

#define SZC   256                            // nodes per bucket
#define NBC   ((N_NODES + SZC - 1) / SZC)    // 391
#define CAPC  9216                           // mean 8192, +11 sigma
#define RND   8192                           // edges per binning round
#define BKT   1024                           // threads per bucket_k block
#define EPT   8                              // edges per thread per round
#define NRND  ((N_EDGES + RND - 1) / RND)    // 391

typedef _Float16 half8 __attribute__((ext_vector_type(8)));
typedef float    f32x4 __attribute__((ext_vector_type(4)));

// ---- int32/int64 index loader (low word of little-endian int64) ----
__device__ __forceinline__ int load_idx(const int* __restrict__ p, long long pos, int is64) {
  return is64 ? p[2 * pos] : p[(int)pos];
}

// unpack 8 consecutive halfs (loaded as float4) and accumulate into a[8]
__device__ __forceinline__ void h8_acc(float4 raw, float* a) {
  const __half2* ph = (const __half2*)&raw;
#pragma unroll
  for (int q = 0; q < 4; q++) {
    float2 f = __half22float2(ph[q]);
    a[2 * q]     += f.x;
    a[2 * q + 1] += f.y;
  }
}

// Detect whether index buffers are int64. block 0 -> ei flag, block 1 -> batch.
__global__ void detect_i64(const int* __restrict__ ei, const int* __restrict__ batch,
                           int* __restrict__ flag) {
  __shared__ int any_nz;
  const int* buf = (blockIdx.x == 0) ? ei : batch;
  if (threadIdx.x == 0) any_nz = 0;
  __syncthreads();
  for (int i = threadIdx.x; i < 4096; i += 256) {
    if (buf[2 * i + 1] != 0) any_nz = 1;
  }
  __syncthreads();
  if (threadIdx.x == 0) flag[blockIdx.x] = any_nz ? 0 : 1;
}

// ---- pack W[K][32] f32 into MFMA B-fragment order, fp16 ----
__global__ void pack_w(const float* __restrict__ W1, const float* __restrict__ W2,
                       const float* __restrict__ W3, __half* __restrict__ P1,
                       __half* __restrict__ P2, __half* __restrict__ P3) {
  int t = threadIdx.x;
  for (int idx = t; idx < 4 * 2 * 64 * 8; idx += 256) {   // W1: K=128 -> 4 k-steps
    int j = idx & 7, l = (idx >> 3) & 63, ct = (idx >> 9) & 1, s = idx >> 10;
    int k = s * 32 + (l >> 4) * 8 + j, c = ct * 16 + (l & 15);
    P1[idx] = __float2half(W1[k * 32 + c]);
  }
  for (int idx = t; idx < 2 * 64 * 8; idx += 256) {       // W2,W3: K=32 -> 1 k-step
    int j = idx & 7, l = (idx >> 3) & 63, ct = (idx >> 9) & 1;
    int k = (l >> 4) * 8 + j, c = ct * 16 + (l & 15);
    P2[idx] = __float2half(W2[k * 32 + c]);
    P3[idx] = __float2half(W3[k * 32 + c]);
  }
}

// ---- pass 1: round-based binning. 391 blocks x 1024 threads (16 waves/block,
//      ~16-32 waves/CU resident) keeps global reservation atomics at
//      391x391 = 153K (1 per round-bucket) with ~21-edge dense runs, while
//      getting occupancy from block WIDTH instead of block COUNT (R11 lesson:
//      atomics scale with blocks x buckets — don't split rounds smaller). ----
__global__ void bucket_k(const int* __restrict__ ei, const int* __restrict__ flag,
                         int* __restrict__ gcur, int* __restrict__ bstore) {
  __shared__ int hist[NBC];
  __shared__ int base[NBC];
  int is64 = flag[0];
  int t = threadIdx.x;
  int rd = blockIdx.x;
  for (int i = t; i < NBC; i += BKT) hist[i] = 0;
  __syncthreads();
  long long e0 = (long long)rd * RND;
  int   pk[EPT];
  short cb[EPT];
#pragma unroll
  for (int k = 0; k < EPT; k++) {
    long long e = e0 + k * BKT + t;
    if (e < N_EDGES) {
      int s = load_idx(ei, e, is64);
      int d = load_idx(ei, N_EDGES + e, is64);
      pk[k] = (s << 8) | (d & 255);
      cb[k] = (short)(d >> 8);
      atomicAdd(&hist[d >> 8], 1);
    } else {
      cb[k] = -1;
    }
  }
  __syncthreads();
  for (int c = t; c < NBC; c += BKT) {
    int h = hist[c];
    if (h > 0) base[c] = atomicAdd(&gcur[c], h);
  }
  __syncthreads();
#pragma unroll
  for (int k = 0; k < EPT; k++) {
    if (cb[k] >= 0) {
      int c = cb[k];
      int pos = atomicAdd(&base[c], 1);          // LDS cursor from global base
      if (pos < CAPC) bstore[(size_t)c * CAPC + pos] = pk[k];
    }
  }
}

// ---- exclusive scan of clamped coarse-bucket counts -> global bases ----
__global__ void bscan_k(const int* __restrict__ gcur, int* __restrict__ bbase) {
  __shared__ int part[256];
  int t = threadIdx.x;
  const int CHUNK = (NBC + 255) / 256;  // 2
  int v[CHUNK];
  int s = 0;
  int base = t * CHUNK;
  for (int k = 0; k < CHUNK; k++) {
    int i = base + k;
    v[k] = (i < NBC) ? min(gcur[i], CAPC) : 0;
    s += v[k];
  }
  part[t] = s;
  __syncthreads();
  if (t == 0) {
    int run = 0;
    for (int i = 0; i < 256; i++) { int x = part[i]; part[i] = run; run += x; }
  }
  __syncthreads();
  int run = part[t];
  for (int k = 0; k < CHUNK; k++) {
    int i = base + k;
    if (i < NBC) bbase[i] = run;
    run += v[k];
  }
}

// ---- per-bucket LDS counting sort -> per-node CSR + deg + dinv ----
__global__ void build_csr(const int* __restrict__ bstore, const int* __restrict__ gcur,
                          const int* __restrict__ bbase, int* __restrict__ csr,
                          int* __restrict__ row_ptr, int* __restrict__ deg,
                          float* __restrict__ dinv) {
  __shared__ int hist[SZC];
  __shared__ int sc[SZC];
  __shared__ int cur[SZC];
  int b = blockIdx.x, t = threadIdx.x;
  hist[t] = 0;
  __syncthreads();
  int cnt = min(gcur[b], CAPC);
  const int* eb = bstore + (size_t)b * CAPC;
  for (int i = t; i < cnt; i += 256) atomicAdd(&hist[eb[i] & 255], 1);
  __syncthreads();
  int own = hist[t];
  sc[t] = own;
  __syncthreads();
  for (int off = 1; off < SZC; off <<= 1) {
    int u = (t >= off) ? sc[t - off] : 0;
    __syncthreads();
    sc[t] += u;
    __syncthreads();
  }
  int excl = sc[t] - own;
  int gbase = bbase[b];
  int node = b * SZC + t;
  if (node < N_NODES) {
    row_ptr[node] = gbase + excl;
    deg[node]     = own;
    dinv[node]    = rsqrtf((float)(own + 1));  // +1 self-loop
  }
  cur[t] = excl;
  __syncthreads();
  for (int i = t; i < cnt; i += 256) {
    int pk = eb[i];                              // L2-hot (same block re-read)
    int pos = atomicAdd(&cur[pk & 255], 1);
    csr[gbase + pos] = pk >> 8;                  // dense ~33KB region, L2-resident
  }
}

// ---- MFMA GEMM: G = fp16( (X @ W) * dinv[row] ), no LDS, no barriers ----
template <int K>
__global__ void gemm_mfma(const float* __restrict__ X, const __half* __restrict__ P,
                          const float* __restrict__ dinv, __half* __restrict__ G) {
  int wid  = threadIdx.x >> 6;
  int lane = threadIdx.x & 63;
  int row0 = (blockIdx.x * 4 + wid) * 16;
  if (row0 >= N_NODES) return;
  int r  = lane & 15;    // A row within tile
  int ko = lane >> 4;    // k-octet selector
  f32x4 acc0 = {0.f, 0.f, 0.f, 0.f};
  f32x4 acc1 = {0.f, 0.f, 0.f, 0.f};
  const float* xrow = X + (size_t)(row0 + r) * K + ko * 8;
#pragma unroll
  for (int s = 0; s < K / 32; s++) {
    float4 xa = *(const float4*)(xrow + s * 32);
    float4 xb = *(const float4*)(xrow + s * 32 + 4);
    half8 a;
    a[0] = (_Float16)xa.x; a[1] = (_Float16)xa.y;
    a[2] = (_Float16)xa.z; a[3] = (_Float16)xa.w;
    a[4] = (_Float16)xb.x; a[5] = (_Float16)xb.y;
    a[6] = (_Float16)xb.z; a[7] = (_Float16)xb.w;
    half8 b0 = *(const half8*)(P + ((size_t)(s * 2 + 0) * 64 + lane) * 8);
    half8 b1 = *(const half8*)(P + ((size_t)(s * 2 + 1) * 64 + lane) * 8);
    acc0 = __builtin_amdgcn_mfma_f32_16x16x32_f16(a, b0, acc0, 0, 0, 0);
    acc1 = __builtin_amdgcn_mfma_f32_16x16x32_f16(a, b1, acc1, 0, 0, 0);
  }
  int col   = lane & 15;
  int rbase = row0 + (lane >> 4) * 4;
#pragma unroll
  for (int i = 0; i < 4; i++) {
    float dn = dinv[rbase + i];
    G[(size_t)(rbase + i) * 32 + col]      = __float2half(acc0[i] * dn);
    G[(size_t)(rbase + i) * 32 + 16 + col] = __float2half(acc1[i] * dn);
  }
}

// ---- pull aggregation: TWO 4-lane groups per node (even/odd edge halves),
//      8 nodes/wave, 12500 waves, 8 outstanding gathers per node ----
__global__ void agg_pull(const __half* __restrict__ g, const int* __restrict__ csr,
                         const int* __restrict__ row_ptr, const int* __restrict__ deg,
                         const float* __restrict__ dinv, const float* __restrict__ bias,
                         float* __restrict__ out, int do_relu) {
  int node = blockIdx.x * 32 + (threadIdx.x >> 3);
  if (node >= N_NODES) return;
  int half = (threadIdx.x >> 2) & 1;   // which half of the edge list
  int j    = threadIdx.x & 3;          // feature octet: halfs [j*8, j*8+8)
  const __half* gj = g + j * 8;
  int start = row_ptr[node];
  int dn = deg[node];
  float a0[8] = {0.f, 0.f, 0.f, 0.f, 0.f, 0.f, 0.f, 0.f};
  float a1[8] = {0.f, 0.f, 0.f, 0.f, 0.f, 0.f, 0.f, 0.f};
  float a2[8] = {0.f, 0.f, 0.f, 0.f, 0.f, 0.f, 0.f, 0.f};
  float a3[8] = {0.f, 0.f, 0.f, 0.f, 0.f, 0.f, 0.f, 0.f};
  int i = half;
  for (; i + 6 < dn; i += 8) {        // stride-2 within half, unroll 4
    int s0 = csr[start + i];
    int s1 = csr[start + i + 2];
    int s2 = csr[start + i + 4];
    int s3 = csr[start + i + 6];
    float4 r0 = *(const float4*)(gj + (size_t)s0 * HID);
    float4 r1 = *(const float4*)(gj + (size_t)s1 * HID);
    float4 r2 = *(const float4*)(gj + (size_t)s2 * HID);
    float4 r3 = *(const float4*)(gj + (size_t)s3 * HID);
    h8_acc(r0, a0);
    h8_acc(r1, a1);
    h8_acc(r2, a2);
    h8_acc(r3, a3);
  }
  for (; i < dn; i += 2) {
    int s0 = csr[start + i];
    h8_acc(*(const float4*)(gj + (size_t)s0 * HID), a0);
  }
#pragma unroll
  for (int k = 0; k < 8; k++) a0[k] += a1[k] + a2[k] + a3[k];
  // combine the two half-streams (lanes differ in bit 2)
#pragma unroll
  for (int k = 0; k < 8; k++) a0[k] += __shfl_xor(a0[k], 4, 64);
  if (half == 0) {
    float self[8] = {0.f, 0.f, 0.f, 0.f, 0.f, 0.f, 0.f, 0.f};
    h8_acc(*(const float4*)(gj + (size_t)node * HID), self);
    float dnv = dinv[node];
    float4 bb0 = *(const float4*)(bias + j * 8);
    float4 bb1 = *(const float4*)(bias + j * 8 + 4);
    float bbv[8] = {bb0.x, bb0.y, bb0.z, bb0.w, bb1.x, bb1.y, bb1.z, bb1.w};
    float r[8];
#pragma unroll
    for (int k = 0; k < 8; k++) {
      r[k] = dnv * (a0[k] + self[k]) + bbv[k];
      if (do_relu) r[k] = fmaxf(r[k], 0.f);
    }
    *(float4*)(out + (size_t)node * HID + j * 8)     = make_float4(r[0], r[1], r[2], r[3]);
    *(float4*)(out + (size_t)node * HID + j * 8 + 4) = make_float4(r[4], r[5], r[6], r[7]);
  }
}

// ---- fused mean-pool + linear head; batch is SORTED -> contiguous ranges ----
__global__ void pool_head(const float* __restrict__ h, const int* __restrict__ batch,
                          const int* __restrict__ flag, const float* __restrict__ Wl,
                          const float* __restrict__ bl, float* __restrict__ out) {
  __shared__ float acc[8][HID];
  int g = blockIdx.x, t = threadIdx.x;
  int is64 = flag[1];
  int start, end;
  {
    int lo = 0, hi = N_NODES;
    while (lo < hi) { int m = (lo + hi) >> 1; if (load_idx(batch, m, is64) < g) lo = m + 1; else hi = m; }
    start = lo;
    lo = start; hi = N_NODES;
    while (lo < hi) { int m = (lo + hi) >> 1; if (load_idx(batch, m, is64) < g + 1) lo = m + 1; else hi = m; }
    end = lo;
  }
  int c = t & 31, r = t >> 5;
  float s = 0.f;
  for (int i = start + r; i < end; i += 8) s += h[(size_t)i * HID + c];
  acc[r][c] = s;
  __syncthreads();
  if (t < HID) {
    float v = 0.f;
#pragma unroll
    for (int q = 0; q < 8; q++) v += acc[q][t];
    acc[0][t] = v / fmaxf((float)(end - start), 1.0f);
  }
  __syncthreads();
  if (t < OUT_CH) {
    float o = bl[t];
#pragma unroll
    for (int k = 0; k < HID; k++) o += acc[0][k] * Wl[k * OUT_CH + t];
    out[g * OUT_CH + t] = o;
  }
}

extern "C" void kernel_launch(void* const* d_in, const int* in_sizes, int n_in,
                              void* d_out, int out_size, void* d_ws, size_t ws_size,
                              hipStream_t stream) {
  const float* x   = (const float*)d_in[0];
  const int* ei    = (const int*)d_in[1];
  const int* batch = (const int*)d_in[2];
  const float* W1  = (const float*)d_in[3];
  const float* b1  = (const float*)d_in[4];
  const float* W2  = (const float*)d_in[5];
  const float* b2  = (const float*)d_in[6];
  const float* W3  = (const float*)d_in[7];
  const float* b3  = (const float*)d_in[8];
  const float* Wl  = (const float*)d_in[9];
  const float* bl  = (const float*)d_in[10];
  float* out = (float*)d_out;

  char* p = (char*)d_ws;
  auto alloc = [&](size_t bytes) {
    void* r = (void*)p;
    p += (bytes + 255) & ~(size_t)255;
    return r;
  };
  int*    gcur    = (int*)alloc((size_t)NBC * 4);
  int*    bbase   = (int*)alloc((size_t)NBC * 4);
  int*    bstore  = (int*)alloc((size_t)NBC * CAPC * 4);  // 14.4 MB
  int*    csr     = (int*)alloc((size_t)N_EDGES * 4);     // 12.8 MB
  int*    row_ptr = (int*)alloc((size_t)N_NODES * 4);
  int*    deg     = (int*)alloc((size_t)N_NODES * 4);
  float*  dinv    = (float*)alloc((size_t)N_NODES * 4);
  int*    flag    = (int*)alloc(8);
  __half* g       = (__half*)alloc((size_t)N_NODES * HID * 2);  // 6.4 MB fp16
  float*  h       = (float*)alloc((size_t)N_NODES * HID * 4);
  __half* P1      = (__half*)alloc((size_t)4 * 2 * 64 * 8 * 2); // 8 KB
  __half* P2      = (__half*)alloc((size_t)2 * 64 * 8 * 2);     // 2 KB
  __half* P3      = (__half*)alloc((size_t)2 * 64 * 8 * 2);     // 2 KB

  hipMemsetAsync(gcur, 0, (size_t)NBC * 4, stream);

  detect_i64<<<2, 256, 0, stream>>>(ei, batch, flag);
  pack_w<<<1, 256, 0, stream>>>(W1, W2, W3, P1, P2, P3);
  bucket_k<<<NRND, BKT, 0, stream>>>(ei, flag, gcur, bstore);
  bscan_k<<<1, 256, 0, stream>>>(gcur, bbase);
  build_csr<<<NBC, 256, 0, stream>>>(bstore, gcur, bbase, csr, row_ptr, deg, dinv);

  const int GB = (N_NODES / 16 + 3) / 4;   // 1563 blocks for gemm
  const int AB = (N_NODES + 31) / 32;      // 3125 blocks for agg (8 nodes/wave)
  gemm_mfma<IN_CH><<<GB, 256, 0, stream>>>(x, P1, dinv, g);
  agg_pull<<<AB, 256, 0, stream>>>(g, csr, row_ptr, deg, dinv, b1, h, 1);
  gemm_mfma<HID><<<GB, 256, 0, stream>>>(h, P2, dinv, g);
  agg_pull<<<AB, 256, 0, stream>>>(g, csr, row_ptr, deg, dinv, b2, h, 1);
  gemm_mfma<HID><<<GB, 256, 0, stream>>>(h, P3, dinv, g);
  agg_pull<<<AB, 256, 0, stream>>>(g, csr, row_ptr, deg, dinv, b3, h, 0);

  pool_head<<<N_GRAPHS, 256, 0, stream>>>(h, batch, flag, Wl, bl, out);
}